// Round 1
// baseline (283.656 us; speedup 1.0000x reference)
//
#include <hip/hip_runtime.h>
#include <cstdint>
#include <cstddef>

#define T_SEQ 2048
#define BSZ 4
#define EMB 512
#define NH 8
#define HD 64
#define SCALING 0.125f
#define NEGBIG (-1e30f)

typedef short bf16x8_t __attribute__((ext_vector_type(8)));
typedef float f32x4_t __attribute__((ext_vector_type(4)));
typedef short short4v __attribute__((ext_vector_type(4)));
typedef float float4v __attribute__((ext_vector_type(4)));

typedef __attribute__((address_space(1))) const void* as1_cvp;
typedef __attribute__((address_space(3))) void* as3_vp;

#define MFMA16(a, b, c) __builtin_amdgcn_mfma_f32_16x16x32_bf16((a), (b), (c), 0, 0, 0)

static __device__ __forceinline__ short f2b(float f) {
  union { float f; uint32_t u; } x; x.f = f;
  uint32_t r = (x.u + 0x7fffu + ((x.u >> 16) & 1u)) >> 16;  // RNE f32->bf16
  return (short)(r & 0xffffu);
}

static __device__ __forceinline__ void gload_lds16(const void* g, void* l) {
  __builtin_amdgcn_global_load_lds((as1_cvp)g, (as3_vp)l, 16, 0, 0);
}

// ---------------------------------------------------------------------------
// f32 -> bf16 conversion, 1024 elems per 256-thread block (float4 in, 4x bf16 out)
// ---------------------------------------------------------------------------
__global__ __launch_bounds__(256) void cvt_kernel(const float* __restrict__ in,
                                                  short* __restrict__ out) {
  int i = (blockIdx.x * 256 + threadIdx.x) * 4;
  float4v v = *(const float4v*)(in + i);
  short4v o;
  o[0] = f2b(v[0]); o[1] = f2b(v[1]); o[2] = f2b(v[2]); o[3] = f2b(v[3]);
  *(short4v*)(out + i) = o;
}

// ---------------------------------------------------------------------------
// NT bf16 GEMM, 128x128 tile, 4 waves (2x2 of 64x64), BK=32, K=512 fixed.
// A [M,512] row-major bf16, Bt [N,512] row-major bf16 (i.e. B transposed).
// EPI 0: QKV scatter epilogue (bias add, write bf16 to per-head Q/K/V layouts)
// EPI 1: out-proj epilogue (bias add, write f32 to [row*512+col])
// ---------------------------------------------------------------------------
template <int EPI>
__global__ __launch_bounds__(256)
void gemm_bt(const short* __restrict__ A, const short* __restrict__ Bt,
             const float* __restrict__ bias,
             short* __restrict__ outQ, short* __restrict__ outK, short* __restrict__ outV,
             float* __restrict__ outF) {
  __shared__ short ldsA[128 * 32];
  __shared__ short ldsB[128 * 32];
  const int tid = threadIdx.x;
  const int wid = tid >> 6, lane = tid & 63, g = lane >> 4, r16 = lane & 15;
  const int wr = wid >> 1, wc = wid & 1;
  const int mbase = blockIdx.y * 128, nbase = blockIdx.x * 128;

  f32x4_t acc[4][4];
#pragma unroll
  for (int m = 0; m < 4; ++m)
#pragma unroll
    for (int n = 0; n < 4; ++n) acc[m][n] = (f32x4_t){0.f, 0.f, 0.f, 0.f};

  for (int kt = 0; kt < 16; ++kt) {
    __syncthreads();
#pragma unroll
    for (int i = 0; i < 2; ++i) {
      int c = i * 256 + tid;
      int row = c >> 2, j4 = c & 3;
      gload_lds16(A + (size_t)(mbase + row) * 512 + kt * 32 + j4 * 8, &ldsA[c * 8]);
      gload_lds16(Bt + (size_t)(nbase + row) * 512 + kt * 32 + j4 * 8, &ldsB[c * 8]);
    }
    __syncthreads();
    bf16x8_t af[4], bfv[4];
#pragma unroll
    for (int m = 0; m < 4; ++m)
      af[m] = *(const bf16x8_t*)&ldsA[(wr * 64 + m * 16 + r16) * 32 + g * 8];
#pragma unroll
    for (int n = 0; n < 4; ++n)
      bfv[n] = *(const bf16x8_t*)&ldsB[(wc * 64 + n * 16 + r16) * 32 + g * 8];
#pragma unroll
    for (int m = 0; m < 4; ++m)
#pragma unroll
      for (int n = 0; n < 4; ++n) acc[m][n] = MFMA16(af[m], bfv[n], acc[m][n]);
  }

#pragma unroll
  for (int m = 0; m < 4; ++m) {
#pragma unroll
    for (int n = 0; n < 4; ++n) {
      int col = nbase + wc * 64 + n * 16 + r16;
      float bcol = bias[col];
#pragma unroll
      for (int j = 0; j < 4; ++j) {
        int row = mbase + wr * 64 + m * 16 + g * 4 + j;  // C layout: row=(lane>>4)*4+j
        float v = acc[m][n][j] + bcol;
        if (EPI == 0) {
          int sect = col >> 9, e = col & 511, hh = e >> 6, d = e & 63;
          int t = row >> 2, b = row & 3;
          size_t dst = ((size_t)(b * NH + hh) * T_SEQ + t) * HD + d;
          short bv = f2b(v);
          if (sect == 0) outQ[dst] = bv;
          else if (sect == 1) outK[dst] = bv;
          else outV[dst] = bv;
        } else {
          outF[(size_t)row * EMB + col] = v;
        }
      }
    }
  }
}

// ---------------------------------------------------------------------------
// Fused causal attention per (head, 64-row query tile).
// 4 waves x 16 query rows. Two passes over key tiles (64 keys each):
//   pass 1: QK^T -> running row max m, row sum l (online)
//   pass 2: QK^T again -> P = exp(S-m)/l, write P f32 to global, P bf16 -> LDS,
//           PV MFMA accumulate. Then O write + upper-triangle zero fill.
// K tile staged via global_load_lds with XOR-swizzled source (rows are 128B).
// V tile reg-staged transposed into [d][key] (padded rows) for key-major reads.
// ---------------------------------------------------------------------------
__global__ __launch_bounds__(256)
void attn_fused(const short* __restrict__ Qg, const short* __restrict__ Kg,
                const short* __restrict__ Vg, float* __restrict__ Pout,
                short* __restrict__ attnO) {
  __shared__ short Kt[64 * 64];
  __shared__ short Vt[64 * 72];      // [d][key], pad 72 to spread banks
  __shared__ short Pl[4][16 * 72];   // per-wave P tile [row][key], pad 72
  const int bh = blockIdx.y;
  const int qt = 31 - (int)blockIdx.x;  // longest blocks dispatch first
  const int tid = threadIdx.x, wid = tid >> 6, lane = tid & 63;
  const int g = lane >> 4, r16 = lane & 15;
  const size_t headOff = (size_t)bh * T_SEQ * HD;

  bf16x8_t qf[2];
  {
    const short* qp = Qg + headOff + (size_t)(qt * 64 + wid * 16 + r16) * HD + g * 8;
    qf[0] = *(const bf16x8_t*)qp;
    qf[1] = *(const bf16x8_t*)(qp + 32);
  }
  int trow[4];
#pragma unroll
  for (int j = 0; j < 4; ++j) trow[j] = qt * 64 + wid * 16 + g * 4 + j;

  float m_r[4] = {NEGBIG, NEGBIG, NEGBIG, NEGBIG};
  float l_r[4] = {0.f, 0.f, 0.f, 0.f};
  const int nkt = qt + 1;

  // ---------------- pass 1: softmax stats ----------------
  for (int kt = 0; kt < nkt; ++kt) {
    const int kb = kt * 64;
    __syncthreads();
#pragma unroll
    for (int i = 0; i < 2; ++i) {
      int c = i * 256 + tid;
      int row = c >> 3, j8 = (c & 7) ^ (row & 7);  // inverse-swizzled source
      gload_lds16(Kg + headOff + (size_t)(kb + row) * HD + j8 * 8, &Kt[c * 8]);
    }
    __syncthreads();
    float sv[4][4];
#pragma unroll
    for (int kc = 0; kc < 4; ++kc) {
      f32x4_t s = {0.f, 0.f, 0.f, 0.f};
#pragma unroll
      for (int kk = 0; kk < 2; ++kk) {
        int rl = kc * 16 + r16;
        int byteo = ((rl * 64 + kk * 32 + g * 8) * 2) ^ ((rl & 7) << 4);
        bf16x8_t kf = *(const bf16x8_t*)((const char*)Kt + byteo);
        s = MFMA16(qf[kk], kf, s);
      }
      int col = kb + kc * 16 + r16;
#pragma unroll
      for (int j = 0; j < 4; ++j)
        sv[kc][j] = (col <= trow[j]) ? s[j] * SCALING : NEGBIG;
    }
#pragma unroll
    for (int j = 0; j < 4; ++j) {
      float pm = fmaxf(fmaxf(sv[0][j], sv[1][j]), fmaxf(sv[2][j], sv[3][j]));
#pragma unroll
      for (int off = 1; off < 16; off <<= 1) pm = fmaxf(pm, __shfl_xor(pm, off));
      float mn = fmaxf(m_r[j], pm);
      float ssum = __expf(sv[0][j] - mn) + __expf(sv[1][j] - mn) +
                   __expf(sv[2][j] - mn) + __expf(sv[3][j] - mn);
#pragma unroll
      for (int off = 1; off < 16; off <<= 1) ssum += __shfl_xor(ssum, off);
      l_r[j] = l_r[j] * __expf(m_r[j] - mn) + ssum;
      m_r[j] = mn;
    }
  }
  float rl_r[4];
#pragma unroll
  for (int j = 0; j < 4; ++j) rl_r[j] = 1.0f / l_r[j];

  f32x4_t oacc[4];
#pragma unroll
  for (int dc = 0; dc < 4; ++dc) oacc[dc] = (f32x4_t){0.f, 0.f, 0.f, 0.f};

  // ---------------- pass 2: P write + PV ----------------
  for (int kt = 0; kt < nkt; ++kt) {
    const int kb = kt * 64;
    __syncthreads();
#pragma unroll
    for (int i = 0; i < 2; ++i) {
      int c = i * 256 + tid;
      int row = c >> 3, j8 = (c & 7) ^ (row & 7);
      gload_lds16(Kg + headOff + (size_t)(kb + row) * HD + j8 * 8, &Kt[c * 8]);
    }
#pragma unroll
    for (int i = 0; i < 2; ++i) {  // V transpose reg-staging
      int c = i * 256 + tid;
      int key = c >> 3, d0 = (c & 7) * 8;
      bf16x8_t v = *(const bf16x8_t*)(Vg + headOff + (size_t)(kb + key) * HD + d0);
#pragma unroll
      for (int jj = 0; jj < 8; ++jj) Vt[(d0 + jj) * 72 + key] = v[jj];
    }
    __syncthreads();
#pragma unroll
    for (int kc = 0; kc < 4; ++kc) {
      f32x4_t s = {0.f, 0.f, 0.f, 0.f};
#pragma unroll
      for (int kk = 0; kk < 2; ++kk) {
        int rl = kc * 16 + r16;
        int byteo = ((rl * 64 + kk * 32 + g * 8) * 2) ^ ((rl & 7) << 4);
        bf16x8_t kf = *(const bf16x8_t*)((const char*)Kt + byteo);
        s = MFMA16(qf[kk], kf, s);
      }
      int col = kb + kc * 16 + r16;
#pragma unroll
      for (int j = 0; j < 4; ++j) {
        float pv = (col <= trow[j]) ? __expf(s[j] * SCALING - m_r[j]) * rl_r[j] : 0.f;
        Pout[((size_t)bh * T_SEQ + trow[j]) * T_SEQ + col] = pv;
        Pl[wid][(g * 4 + j) * 72 + kc * 16 + r16] = f2b(pv);
      }
    }
    __syncthreads();  // Pl visible across lanes of the wave (and uniform barrier)
#pragma unroll
    for (int kc2 = 0; kc2 < 2; ++kc2) {
      bf16x8_t pf = *(const bf16x8_t*)&Pl[wid][r16 * 72 + kc2 * 32 + g * 8];
#pragma unroll
      for (int dc = 0; dc < 4; ++dc) {
        bf16x8_t vf = *(const bf16x8_t*)&Vt[(dc * 16 + r16) * 72 + kc2 * 32 + g * 8];
        oacc[dc] = MFMA16(pf, vf, oacc[dc]);
      }
    }
  }

  // O write -> attn buffer [tok][E] bf16 for the out-projection GEMM
#pragma unroll
  for (int dc = 0; dc < 4; ++dc) {
#pragma unroll
    for (int j = 0; j < 4; ++j) {
      int t = trow[j], d = dc * 16 + r16;
      size_t ntok = (size_t)t * BSZ + (bh >> 3);
      attnO[ntok * EMB + (bh & 7) * HD + d] = f2b(oacc[dc][j]);
    }
  }

  // zero-fill strictly-upper region beyond the processed tiles
  const int c0 = nkt * 64;
  const int nc4 = (T_SEQ - c0) >> 2;
  for (int r = 0; r < 64; ++r) {
    size_t base = ((size_t)bh * T_SEQ + qt * 64 + r) * T_SEQ + c0;
    for (int c4 = tid; c4 < nc4; c4 += 256) {
      float4v z = {0.f, 0.f, 0.f, 0.f};
      *(float4v*)(Pout + base + (size_t)c4 * 4) = z;
    }
  }
}

// ---------------------------------------------------------------------------
extern "C" void kernel_launch(void* const* d_in, const int* in_sizes, int n_in,
                              void* d_out, int out_size, void* d_ws, size_t ws_size,
                              hipStream_t stream) {
  const float* h = (const float*)d_in[0];
  // d_in[1] = attn_mask (causal, applied structurally)
  const float* w_in = (const float*)d_in[2];
  const float* b_in = (const float*)d_in[3];
  const float* w_out = (const float*)d_in[4];
  const float* b_out = (const float*)d_in[5];
  float* out = (float*)d_out;
  float* Pout = out + (size_t)T_SEQ * BSZ * EMB;

  short* hB = (short*)d_ws;                      // 8192*512 bf16
  short* wB = hB + (size_t)8192 * 512;           // 1536*512
  short* owB = wB + (size_t)1536 * 512;          // 512*512
  short* qB = owB + (size_t)512 * 512;           // 32*2048*64 per-head
  short* kB = qB + (size_t)32 * 2048 * 64;
  short* vB = kB + (size_t)32 * 2048 * 64;
  short* aB = vB + (size_t)32 * 2048 * 64;       // 8192*512

  cvt_kernel<<<4096, 256, 0, stream>>>(h, hB);
  cvt_kernel<<<768, 256, 0, stream>>>(w_in, wB);
  cvt_kernel<<<256, 256, 0, stream>>>(w_out, owB);

  gemm_bt<0><<<dim3(12, 64), 256, 0, stream>>>(hB, wB, b_in, qB, kB, vB, nullptr);
  attn_fused<<<dim3(32, 32), 256, 0, stream>>>(qB, kB, vB, Pout, aB);
  gemm_bt<1><<<dim3(4, 64), 256, 0, stream>>>(aB, owB, b_out, nullptr, nullptr, nullptr, out);
}

// Round 2
// 230.580 us; speedup vs baseline: 1.2302x; 1.2302x over previous
//
#include <hip/hip_runtime.h>
#include <cstdint>
#include <cstddef>

#define T_SEQ 2048
#define BSZ 4
#define EMB 512
#define NH 8
#define HD 64
#define SCALING 0.125f
#define NEGBIG (-1e30f)
#define KVB 128
#define PW 136   // padded short-row width for Vt/Pl (byte stride 272 = 16-aligned)

typedef short bf16x8_t __attribute__((ext_vector_type(8)));
typedef float f32x4_t __attribute__((ext_vector_type(4)));
typedef short short4v __attribute__((ext_vector_type(4)));
typedef float float4v __attribute__((ext_vector_type(4)));

typedef __attribute__((address_space(1))) const void* as1_cvp;
typedef __attribute__((address_space(3))) void* as3_vp;

#define MFMA16(a, b, c) __builtin_amdgcn_mfma_f32_16x16x32_bf16((a), (b), (c), 0, 0, 0)

static __device__ __forceinline__ short f2b(float f) {
  union { float f; uint32_t u; } x; x.f = f;
  uint32_t r = (x.u + 0x7fffu + ((x.u >> 16) & 1u)) >> 16;  // RNE f32->bf16
  return (short)(r & 0xffffu);
}

static __device__ __forceinline__ void gload_lds16(const void* g, void* l) {
  __builtin_amdgcn_global_load_lds((as1_cvp)g, (as3_vp)l, 16, 0, 0);
}

// ---------------------------------------------------------------------------
// f32 -> bf16 conversion
// ---------------------------------------------------------------------------
__global__ __launch_bounds__(256) void cvt_kernel(const float* __restrict__ in,
                                                  short* __restrict__ out) {
  int i = (blockIdx.x * 256 + threadIdx.x) * 4;
  float4v v = *(const float4v*)(in + i);
  short4v o;
  o[0] = f2b(v[0]); o[1] = f2b(v[1]); o[2] = f2b(v[2]); o[3] = f2b(v[3]);
  *(short4v*)(out + i) = o;
}

// ---------------------------------------------------------------------------
// NT bf16 GEMM, 128x128 tile, 4 waves, BK=32, K=512 (unchanged from R1 pass)
// ---------------------------------------------------------------------------
template <int EPI>
__global__ __launch_bounds__(256)
void gemm_bt(const short* __restrict__ A, const short* __restrict__ Bt,
             const float* __restrict__ bias,
             short* __restrict__ outQ, short* __restrict__ outK, short* __restrict__ outV,
             float* __restrict__ outF) {
  __shared__ short ldsA[128 * 32];
  __shared__ short ldsB[128 * 32];
  const int tid = threadIdx.x;
  const int wid = tid >> 6, lane = tid & 63, g = lane >> 4, r16 = lane & 15;
  const int wr = wid >> 1, wc = wid & 1;
  const int mbase = blockIdx.y * 128, nbase = blockIdx.x * 128;

  f32x4_t acc[4][4];
#pragma unroll
  for (int m = 0; m < 4; ++m)
#pragma unroll
    for (int n = 0; n < 4; ++n) acc[m][n] = (f32x4_t){0.f, 0.f, 0.f, 0.f};

  for (int kt = 0; kt < 16; ++kt) {
    __syncthreads();
#pragma unroll
    for (int i = 0; i < 2; ++i) {
      int c = i * 256 + tid;
      int row = c >> 2, j4 = c & 3;
      gload_lds16(A + (size_t)(mbase + row) * 512 + kt * 32 + j4 * 8, &ldsA[c * 8]);
      gload_lds16(Bt + (size_t)(nbase + row) * 512 + kt * 32 + j4 * 8, &ldsB[c * 8]);
    }
    __syncthreads();
    bf16x8_t af[4], bfv[4];
#pragma unroll
    for (int m = 0; m < 4; ++m)
      af[m] = *(const bf16x8_t*)&ldsA[(wr * 64 + m * 16 + r16) * 32 + g * 8];
#pragma unroll
    for (int n = 0; n < 4; ++n)
      bfv[n] = *(const bf16x8_t*)&ldsB[(wc * 64 + n * 16 + r16) * 32 + g * 8];
#pragma unroll
    for (int m = 0; m < 4; ++m)
#pragma unroll
      for (int n = 0; n < 4; ++n) acc[m][n] = MFMA16(af[m], bfv[n], acc[m][n]);
  }

#pragma unroll
  for (int m = 0; m < 4; ++m) {
#pragma unroll
    for (int n = 0; n < 4; ++n) {
      int col = nbase + wc * 64 + n * 16 + r16;
      float bcol = bias[col];
#pragma unroll
      for (int j = 0; j < 4; ++j) {
        int row = mbase + wr * 64 + m * 16 + g * 4 + j;
        float v = acc[m][n][j] + bcol;
        if (EPI == 0) {
          int sect = col >> 9, e = col & 511, hh = e >> 6, d = e & 63;
          int t = row >> 2, b = row & 3;
          size_t dst = ((size_t)(b * NH + hh) * T_SEQ + t) * HD + d;
          short bv = f2b(v);
          if (sect == 0) outQ[dst] = bv;
          else if (sect == 1) outK[dst] = bv;
          else outV[dst] = bv;
        } else {
          outF[(size_t)row * EMB + col] = v;
        }
      }
    }
  }
}

// ---------------------------------------------------------------------------
// Fused causal attention per (head, 64-row query tile). KVB=128 key tiles.
// Pass 1: swapped mfma(K,Q) -> S^T layout, per-lane in-register online (m,l),
//         final 2-step shfl_xor merge across the 4 lane-groups per row.
// Pass 2: normal mfma(Q,K) -> coalesced normalized P f32 write + bf16 Pl;
//         PV accumulate. 2 barriers per tile total.
// ---------------------------------------------------------------------------
__global__ __launch_bounds__(256)
void attn_fused(const short* __restrict__ Qg, const short* __restrict__ Kg,
                const short* __restrict__ Vg, float* __restrict__ Pout,
                short* __restrict__ attnO) {
  __shared__ short Kt[KVB * 64];     // XOR-swizzled rows (128B each)
  __shared__ short Vt[64 * PW];      // [d][key], key-pairs packed via b32 writes
  __shared__ short Pl[4][16 * PW];   // per-wave P tile [qlocal][key]
  const int bh = blockIdx.x;
  const int qt = 31 - (int)blockIdx.y;  // longest blocks dispatch first
  const int tid = threadIdx.x, wid = tid >> 6, lane = tid & 63;
  const int g = lane >> 4, r16 = lane & 15;
  const size_t headOff = (size_t)bh * T_SEQ * HD;
  const int wrow0 = qt * 64 + wid * 16;   // wave's first q row
  const int maxcol = qt * 64 + 64;        // exclusive covered-column bound
  const int nkt = (qt >> 1) + 1;          // 128-key tiles

  bf16x8_t qf[2];
  {
    const short* qp = Qg + headOff + (size_t)(wrow0 + r16) * HD + g * 8;
    qf[0] = *(const bf16x8_t*)qp;
    qf[1] = *(const bf16x8_t*)(qp + 32);
  }

  // ---------------- pass 1: stats via swapped QK^T ----------------
  float m1 = NEGBIG, l1 = 0.f;
  const int myrow = wrow0 + r16;
  for (int kt = 0; kt < nkt; ++kt) {
    const int kb = kt * KVB;
    const int navail = (maxcol - kb) >> 4;
    const int nkc = navail < 8 ? navail : 8;
    __syncthreads();
#pragma unroll
    for (int i = 0; i < 4; ++i) {
      int c = i * 256 + tid;
      int row = c >> 3, j8 = (c & 7) ^ (row & 7);
      gload_lds16(Kg + headOff + (size_t)(kb + row) * HD + j8 * 8, &Kt[c * 8]);
    }
    __syncthreads();
    float sv[8][4];
#pragma unroll
    for (int kc = 0; kc < 8; ++kc) {
      if (kc < nkc) {
        f32x4_t s = {0.f, 0.f, 0.f, 0.f};
        const int rl = kc * 16 + r16;
#pragma unroll
        for (int kk = 0; kk < 2; ++kk) {
          int byteo = (rl * 128 + kk * 64 + g * 16) ^ ((rl & 7) << 4);
          bf16x8_t kf = *(const bf16x8_t*)((const char*)Kt + byteo);
          s = MFMA16(kf, qf[kk], s);  // swapped: D[key][q]
        }
        const bool nomask = (kb + kc * 16 + 15 <= wrow0);
#pragma unroll
        for (int j = 0; j < 4; ++j) {
          int key = kb + kc * 16 + g * 4 + j;
          float v = s[j] * SCALING;
          sv[kc][j] = (nomask || key <= myrow) ? v : NEGBIG;
        }
      }
    }
    float pm = NEGBIG;
#pragma unroll
    for (int kc = 0; kc < 8; ++kc)
      if (kc < nkc) {
#pragma unroll
        for (int j = 0; j < 4; ++j) pm = fmaxf(pm, sv[kc][j]);
      }
    float mn = fmaxf(m1, pm);
    float sum = 0.f;
#pragma unroll
    for (int kc = 0; kc < 8; ++kc)
      if (kc < nkc) {
#pragma unroll
        for (int j = 0; j < 4; ++j) sum += __expf(sv[kc][j] - mn);
      }
    l1 = l1 * __expf(m1 - mn) + sum;
    m1 = mn;
  }
  // merge the 4 lane-groups (lanes r16, r16+16, r16+32, r16+48 share a row)
#pragma unroll
  for (int off = 16; off <= 32; off <<= 1) {
    float mo = __shfl_xor(m1, off), lo = __shfl_xor(l1, off);
    float mn = fmaxf(m1, mo);
    l1 = l1 * __expf(m1 - mn) + lo * __expf(mo - mn);
    m1 = mn;
  }
  // redistribute to pass-2 row ownership (lane g,r16 owns rows g*4+j)
  float m2[4], rl2[4];
  int trow[4];
#pragma unroll
  for (int j = 0; j < 4; ++j) {
    m2[j] = __shfl(m1, g * 4 + j);
    rl2[j] = 1.0f / __shfl(l1, g * 4 + j);
    trow[j] = wrow0 + g * 4 + j;
  }

  f32x4_t oacc[4];
#pragma unroll
  for (int dc = 0; dc < 4; ++dc) oacc[dc] = (f32x4_t){0.f, 0.f, 0.f, 0.f};

  // ---------------- pass 2: P write + PV ----------------
  uint32_t* Vtu = (uint32_t*)Vt;
  for (int kt = 0; kt < nkt; ++kt) {
    const int kb = kt * KVB;
    const int navail = (maxcol - kb) >> 4;
    const int nkc = navail < 8 ? navail : 8;
    __syncthreads();
#pragma unroll
    for (int i = 0; i < 4; ++i) {
      int c = i * 256 + tid;
      int row = c >> 3, j8 = (c & 7) ^ (row & 7);
      gload_lds16(Kg + headOff + (size_t)(kb + row) * HD + j8 * 8, &Kt[c * 8]);
    }
#pragma unroll
    for (int i = 0; i < 2; ++i) {  // V pair-packed transpose staging
      int c = i * 256 + tid;
      int kp = c & 63, dg = c >> 6;
      const short* vp = Vg + headOff + (size_t)(kb + kp * 2) * HD + dg * 8;
      bf16x8_t va = *(const bf16x8_t*)vp;
      bf16x8_t vb = *(const bf16x8_t*)(vp + HD);
#pragma unroll
      for (int j = 0; j < 8; ++j)
        Vtu[(dg * 8 + j) * (PW / 2) + kp] =
            (uint32_t)(uint16_t)va[j] | ((uint32_t)(uint16_t)vb[j] << 16);
    }
    __syncthreads();
#pragma unroll
    for (int kc = 0; kc < 8; ++kc) {
      if (kc < nkc) {
        f32x4_t s = {0.f, 0.f, 0.f, 0.f};
        const int rl = kc * 16 + r16;
#pragma unroll
        for (int kk = 0; kk < 2; ++kk) {
          int byteo = (rl * 128 + kk * 64 + g * 16) ^ ((rl & 7) << 4);
          bf16x8_t kf = *(const bf16x8_t*)((const char*)Kt + byteo);
          s = MFMA16(qf[kk], kf, s);  // normal: D[q][key]
        }
        int col = kb + kc * 16 + r16;
#pragma unroll
        for (int j = 0; j < 4; ++j) {
          float e = __expf(s[j] * SCALING - m2[j]) * rl2[j];
          float pv = (col <= trow[j]) ? e : 0.f;
          Pout[((size_t)bh * T_SEQ + trow[j]) * T_SEQ + col] = pv;
          Pl[wid][(g * 4 + j) * PW + kc * 16 + r16] = f2b(pv);
        }
      }
    }
    // no barrier: Pl is per-wave (lockstep + lgkmcnt), Vt stable till next top barrier
#pragma unroll
    for (int kc2 = 0; kc2 < 4; ++kc2) {
      if (kc2 < (nkc >> 1)) {
        bf16x8_t pf = *(const bf16x8_t*)&Pl[wid][r16 * PW + kc2 * 32 + g * 8];
#pragma unroll
        for (int dc = 0; dc < 4; ++dc) {
          bf16x8_t vf = *(const bf16x8_t*)&Vt[(dc * 16 + r16) * PW + kc2 * 32 + g * 8];
          oacc[dc] = MFMA16(pf, vf, oacc[dc]);
        }
      }
    }
  }

  // O write -> [tok][E] bf16 for the out-projection GEMM
#pragma unroll
  for (int dc = 0; dc < 4; ++dc) {
#pragma unroll
    for (int j = 0; j < 4; ++j) {
      int t = trow[j], d = dc * 16 + r16;
      size_t ntok = (size_t)t * BSZ + (bh >> 3);
      attnO[ntok * EMB + (bh & 7) * HD + d] = f2b(oacc[dc][j]);
    }
  }

  // zero-fill strictly-upper region beyond covered columns
  const int c0 = maxcol;
  const int nc4 = (T_SEQ - c0) >> 2;
  for (int r = 0; r < 64; ++r) {
    size_t base = ((size_t)bh * T_SEQ + qt * 64 + r) * T_SEQ + c0;
    for (int c4 = tid; c4 < nc4; c4 += 256) {
      float4v z = {0.f, 0.f, 0.f, 0.f};
      *(float4v*)(Pout + base + (size_t)c4 * 4) = z;
    }
  }
}

// ---------------------------------------------------------------------------
extern "C" void kernel_launch(void* const* d_in, const int* in_sizes, int n_in,
                              void* d_out, int out_size, void* d_ws, size_t ws_size,
                              hipStream_t stream) {
  const float* h = (const float*)d_in[0];
  // d_in[1] = attn_mask (causal, applied structurally)
  const float* w_in = (const float*)d_in[2];
  const float* b_in = (const float*)d_in[3];
  const float* w_out = (const float*)d_in[4];
  const float* b_out = (const float*)d_in[5];
  float* out = (float*)d_out;
  float* Pout = out + (size_t)T_SEQ * BSZ * EMB;

  short* hB = (short*)d_ws;                      // 8192*512 bf16
  short* wB = hB + (size_t)8192 * 512;           // 1536*512
  short* owB = wB + (size_t)1536 * 512;          // 512*512
  short* qB = owB + (size_t)512 * 512;           // 32*2048*64 per-head
  short* kB = qB + (size_t)32 * 2048 * 64;
  short* vB = kB + (size_t)32 * 2048 * 64;
  short* aB = vB + (size_t)32 * 2048 * 64;       // 8192*512

  cvt_kernel<<<4096, 256, 0, stream>>>(h, hB);
  cvt_kernel<<<768, 256, 0, stream>>>(w_in, wB);
  cvt_kernel<<<256, 256, 0, stream>>>(w_out, owB);

  gemm_bt<0><<<dim3(12, 64), 256, 0, stream>>>(hB, wB, b_in, qB, kB, vB, nullptr);
  attn_fused<<<dim3(32, 32), 256, 0, stream>>>(qB, kB, vB, Pout, aB);
  gemm_bt<1><<<dim3(4, 64), 256, 0, stream>>>(aB, owB, b_out, nullptr, nullptr, nullptr, out);
}